// Round 1
// baseline (1037.985 us; speedup 1.0000x reference)
//
#include <hip/hip_runtime.h>
#include <stdint.h>

#define B_ 8
#define K_ 8
#define N_ 128
#define D_ 256
#define H_ 128
#define NNEG_ 64
#define NTOP_ 64
#define BK_ 64

// ---------------------------------------------------------------------------
// GEMM: OUT[r,h] = sum_d A[r*D+d] * W[d*H+h].  rows multiple of 64.
// Block: 256 threads (16x16), tile 64 rows x 128 cols, K-chunks of 16.
// ---------------------------------------------------------------------------
__global__ __launch_bounds__(256) void gemm_rxd(const float* __restrict__ A,
                                                const float* __restrict__ W,
                                                float* __restrict__ OUT) {
    __shared__ float As[64][17];
    __shared__ float Bs[16][128];
    int t = threadIdx.x;
    int tx = t & 15, ty = t >> 4;
    int rb = blockIdx.x * 64;
    float acc[4][8];
#pragma unroll
    for (int i = 0; i < 4; ++i)
#pragma unroll
        for (int j = 0; j < 8; ++j) acc[i][j] = 0.f;

    for (int k0 = 0; k0 < D_; k0 += 16) {
        {
            int row = t >> 2, kq = (t & 3) * 4;
            const float4 av = *(const float4*)&A[(size_t)(rb + row) * D_ + k0 + kq];
            As[row][kq + 0] = av.x; As[row][kq + 1] = av.y;
            As[row][kq + 2] = av.z; As[row][kq + 3] = av.w;
        }
        {
            int flat = t * 8;
            int kr = flat >> 7, hc = flat & 127;
            float4 b0 = *(const float4*)&W[(size_t)(k0 + kr) * H_ + hc];
            float4 b1 = *(const float4*)&W[(size_t)(k0 + kr) * H_ + hc + 4];
            *(float4*)&Bs[kr][hc] = b0;
            *(float4*)&Bs[kr][hc + 4] = b1;
        }
        __syncthreads();
#pragma unroll
        for (int kk = 0; kk < 16; ++kk) {
            float a0 = As[ty * 4 + 0][kk], a1 = As[ty * 4 + 1][kk];
            float a2 = As[ty * 4 + 2][kk], a3 = As[ty * 4 + 3][kk];
            float bv[8];
            *(float4*)&bv[0] = *(const float4*)&Bs[kk][tx * 8];
            *(float4*)&bv[4] = *(const float4*)&Bs[kk][tx * 8 + 4];
#pragma unroll
            for (int j = 0; j < 8; ++j) {
                acc[0][j] += a0 * bv[j];
                acc[1][j] += a1 * bv[j];
                acc[2][j] += a2 * bv[j];
                acc[3][j] += a3 * bv[j];
            }
        }
        __syncthreads();
    }
#pragma unroll
    for (int i = 0; i < 4; ++i) {
        float4 o0 = {acc[i][0], acc[i][1], acc[i][2], acc[i][3]};
        float4 o1 = {acc[i][4], acc[i][5], acc[i][6], acc[i][7]};
        *(float4*)&OUT[(size_t)(rb + ty * 4 + i) * H_ + tx * 8] = o0;
        *(float4*)&OUT[(size_t)(rb + ty * 4 + i) * H_ + tx * 8 + 4] = o1;
    }
}

// ---------------------------------------------------------------------------
// ue: t0[bk,m] = (1/64) * sum_n sum_h relu(HU0[bk,m,h]+HU1n[bk,n,h]+bu1[h])*wu2[h] + bu2
// grid (BK, N/32), block 256.  Each thread: 4 m's x 2 n's.
// ---------------------------------------------------------------------------
__global__ __launch_bounds__(256) void ue_kernel(const float* __restrict__ HU0,
                                                 const float* __restrict__ HU1n,
                                                 const float* __restrict__ bu1,
                                                 const float* __restrict__ Wu2,
                                                 const float* __restrict__ bu2v,
                                                 float* __restrict__ t0) {
    __shared__ float Ls[32][129];
    __shared__ float Rs[64][129];
    __shared__ float ws[128];
    __shared__ float red[32][33];
    int bk = blockIdx.x, mt = blockIdx.y;
    int t = threadIdx.x;
    for (int i = t; i < 64 * 128; i += 256) {
        int n = i >> 7, h = i & 127;
        Rs[n][h] = HU1n[(size_t)(bk * NNEG_ + n) * H_ + h];
    }
    for (int i = t; i < 32 * 128; i += 256) {
        int m = i >> 7, h = i & 127;
        Ls[m][h] = HU0[(size_t)(bk * N_ + mt * 32 + m) * H_ + h] + bu1[h];
    }
    if (t < 128) ws[t] = Wu2[t];
    __syncthreads();

    int tm = t & 7;    // m group (4 m's each)
    int tn = t >> 3;   // 0..31, 2 n's each
    const float* l0 = &Ls[tm * 4 + 0][0];
    const float* l1 = &Ls[tm * 4 + 1][0];
    const float* l2 = &Ls[tm * 4 + 2][0];
    const float* l3 = &Ls[tm * 4 + 3][0];
    const float* r0 = &Rs[tn * 2 + 0][0];
    const float* r1 = &Rs[tn * 2 + 1][0];
    float a00 = 0.f, a01 = 0.f, a10 = 0.f, a11 = 0.f;
    float a20 = 0.f, a21 = 0.f, a30 = 0.f, a31 = 0.f;
#pragma unroll 4
    for (int h = 0; h < 128; ++h) {
        float w = ws[h];
        float b0 = r0[h], b1 = r1[h];
        float a0 = l0[h], a1 = l1[h], a2 = l2[h], a3 = l3[h];
        float v;
        v = a0 + b0; v = v > 0.f ? v : 0.f; a00 += v * w;
        v = a0 + b1; v = v > 0.f ? v : 0.f; a01 += v * w;
        v = a1 + b0; v = v > 0.f ? v : 0.f; a10 += v * w;
        v = a1 + b1; v = v > 0.f ? v : 0.f; a11 += v * w;
        v = a2 + b0; v = v > 0.f ? v : 0.f; a20 += v * w;
        v = a2 + b1; v = v > 0.f ? v : 0.f; a21 += v * w;
        v = a3 + b0; v = v > 0.f ? v : 0.f; a30 += v * w;
        v = a3 + b1; v = v > 0.f ? v : 0.f; a31 += v * w;
    }
    red[tm * 4 + 0][tn] = a00 + a01;
    red[tm * 4 + 1][tn] = a10 + a11;
    red[tm * 4 + 2][tn] = a20 + a21;
    red[tm * 4 + 3][tn] = a30 + a31;
    __syncthreads();
    if (t < 32) {
        float s = 0.f;
        for (int q = 0; q < 32; ++q) s += red[t][q];
        t0[bk * N_ + mt * 32 + t] = s * (1.0f / NNEG_) + bu2v[0];
    }
}

// ---------------------------------------------------------------------------
// score+total: total[b, m0*M+m1] = tL[m0] + tR[m1] - (dot(relu(L+R+bp1),wp2)+bp2)
// grid (Bn, M/32, M/64), block 256.
// ---------------------------------------------------------------------------
__global__ __launch_bounds__(256) void score_kernel(
    const float* __restrict__ Lp, int Lbs,
    const float* __restrict__ Rp, int Rbs,
    const float* __restrict__ tLp, int tLbs,
    const float* __restrict__ tRp, int tRbs,
    const float* __restrict__ bp1, const float* __restrict__ Wp2,
    const float* __restrict__ bp2, float* __restrict__ total, int M) {
    int b = blockIdx.x, m0t = blockIdx.y, m1t = blockIdx.z;
    const float* L = Lp + (size_t)b * Lbs + m0t * 32 * H_;
    const float* R = Rp + (size_t)b * Rbs + m1t * 64 * H_;
    __shared__ float Ls[32][129];
    __shared__ float Rs[64][129];
    __shared__ float ws[128];
    int t = threadIdx.x;
    for (int i = t; i < 64 * 128; i += 256) {
        int n = i >> 7, h = i & 127;
        Rs[n][h] = R[(size_t)n * H_ + h];
    }
    for (int i = t; i < 32 * 128; i += 256) {
        int m = i >> 7, h = i & 127;
        Ls[m][h] = L[(size_t)m * H_ + h] + bp1[h];
    }
    if (t < 128) ws[t] = Wp2[t];
    __syncthreads();

    int tm = t & 7, tn = t >> 3;
    const float* l0 = &Ls[tm * 4 + 0][0];
    const float* l1 = &Ls[tm * 4 + 1][0];
    const float* l2 = &Ls[tm * 4 + 2][0];
    const float* l3 = &Ls[tm * 4 + 3][0];
    const float* r0 = &Rs[tn * 2 + 0][0];
    const float* r1 = &Rs[tn * 2 + 1][0];
    float a00 = 0.f, a01 = 0.f, a10 = 0.f, a11 = 0.f;
    float a20 = 0.f, a21 = 0.f, a30 = 0.f, a31 = 0.f;
#pragma unroll 4
    for (int h = 0; h < 128; ++h) {
        float w = ws[h];
        float b0 = r0[h], b1 = r1[h];
        float a0 = l0[h], a1 = l1[h], a2 = l2[h], a3 = l3[h];
        float v;
        v = a0 + b0; v = v > 0.f ? v : 0.f; a00 += v * w;
        v = a0 + b1; v = v > 0.f ? v : 0.f; a01 += v * w;
        v = a1 + b0; v = v > 0.f ? v : 0.f; a10 += v * w;
        v = a1 + b1; v = v > 0.f ? v : 0.f; a11 += v * w;
        v = a2 + b0; v = v > 0.f ? v : 0.f; a20 += v * w;
        v = a2 + b1; v = v > 0.f ? v : 0.f; a21 += v * w;
        v = a3 + b0; v = v > 0.f ? v : 0.f; a30 += v * w;
        v = a3 + b1; v = v > 0.f ? v : 0.f; a31 += v * w;
    }
    float bp2v = bp2[0];
    const float* tL = tLp + (size_t)b * tLbs;
    const float* tR = tRp + (size_t)b * tRbs;
    float* orow = total + (size_t)b * M * M;
    float accs[4][2] = {{a00, a01}, {a10, a11}, {a20, a21}, {a30, a31}};
#pragma unroll
    for (int i = 0; i < 4; ++i) {
        int m0 = m0t * 32 + tm * 4 + i;
        float tl = tL[m0];
#pragma unroll
        for (int j = 0; j < 2; ++j) {
            int m1 = m1t * 64 + tn * 2 + j;
            orow[(size_t)m0 * M + m1] = tl + tR[m1] - (accs[i][j] + bp2v);
        }
    }
}

// ---------------------------------------------------------------------------
// gather: outg[b,m,h] = (1/S) sum_s SRC[(b*2S + c*S + s)*N*H + sub_prev[(2b+c)*64*S + m*S + s]*H + h]
// grid (Bn, 64), block 128.
// ---------------------------------------------------------------------------
__global__ void gather_kernel(const float* __restrict__ SRC,
                              const int* __restrict__ sub_prev,
                              float* __restrict__ outg, int S, int c) {
    int b = blockIdx.x, m = blockIdx.y, h = threadIdx.x;
    const int* srow = sub_prev + (size_t)((2 * b + c) * 64 + m) * S;
    int base_bk = b * 2 * S + c * S;
    float s = 0.f;
    for (int i = 0; i < S; ++i) {
        int leaf = srow[i];
        s += SRC[(size_t)(base_bk + i) * N_ * H_ + (size_t)leaf * H_ + h];
    }
    outg[(size_t)(b * 64 + m) * H_ + h] = s / (float)S;
}

// ---------------------------------------------------------------------------
// stable top-k (ascending value, tie -> lower index): 64 extract-mins.
// key = (sortable_f32 << 32) | idx, strictly increasing across extractions.
// grid (Bn), block 256.
// ---------------------------------------------------------------------------
__global__ __launch_bounds__(256) void topk_kernel(const float* __restrict__ total,
                                                   int L, int topk,
                                                   int* __restrict__ inds) {
    int b = blockIdx.x;
    const float* row = total + (size_t)b * L;
    __shared__ unsigned long long red[256];
    unsigned long long last = 0ull;
    for (int e = 0; e < topk; ++e) {
        unsigned long long lm = 0xFFFFFFFFFFFFFFFFull;
        for (int i = threadIdx.x; i < L; i += 256) {
            unsigned u = __float_as_uint(row[i]);
            u = (u & 0x80000000u) ? ~u : (u | 0x80000000u);
            unsigned long long k = ((unsigned long long)u << 32) | (unsigned)i;
            if (k > last && k < lm) lm = k;
        }
        red[threadIdx.x] = lm;
        __syncthreads();
        for (int sft = 128; sft > 0; sft >>= 1) {
            if (threadIdx.x < sft) {
                if (red[threadIdx.x + sft] < red[threadIdx.x])
                    red[threadIdx.x] = red[threadIdx.x + sft];
            }
            __syncthreads();
        }
        unsigned long long w = red[0];
        if (threadIdx.x == 0) inds[b * 64 + e] = (int)(w & 0xFFFFFFFFull);
        last = w;
        __syncthreads();
    }
}

// ---------------------------------------------------------------------------
// select: propagate totals and subtree leaf lists for the selected candidates.
// S==0 means level 0 (identity sub).  grid (Bn), block 64.
// ---------------------------------------------------------------------------
__global__ void select_kernel(const float* __restrict__ total, int M,
                              const int* __restrict__ inds, int topk,
                              const int* __restrict__ sub_prev, int S,
                              int* __restrict__ sub_new,
                              float* __restrict__ t_new) {
    int b = blockIdx.x;
    int e = threadIdx.x;
    if (e >= topk) return;
    int j = inds[b * 64 + e];
    int p0 = j / M, p1 = j % M;
    t_new[b * 64 + e] = total[(size_t)b * M * M + j];
    int Sp = (S == 0) ? 1 : S;
    int* orow = sub_new + (size_t)(b * topk + e) * 2 * Sp;
    if (S == 0) {
        orow[0] = p0;
        orow[1] = p1;
    } else {
        const int* s0 = sub_prev + (size_t)((2 * b) * 64 + p0) * S;
        const int* s1 = sub_prev + (size_t)((2 * b + 1) * 64 + p1) * S;
        for (int s = 0; s < S; ++s) { orow[s] = s0[s]; orow[S + s] = s1[s]; }
    }
}

// ---------------------------------------------------------------------------
// output: out[0:64] = final leaf indices (as float), out[64:8256] = is_target.
// ---------------------------------------------------------------------------
__global__ void out_kernel(const int* __restrict__ sub_final,
                           const int* __restrict__ pos_classes,
                           const int* __restrict__ target_class,
                           float* __restrict__ out) {
    int t = blockIdx.x * 256 + threadIdx.x;
    if (t < 64) {
        out[t] = (float)sub_final[t];
    } else if (t < 64 + B_ * K_ * N_) {
        int idx = t - 64;
        int bq = idx >> 10;  // / (K_*N_)
        out[t] = (pos_classes[idx] == target_class[bq]) ? 1.0f : 0.0f;
    }
}

extern "C" void kernel_launch(void* const* d_in, const int* in_sizes, int n_in,
                              void* d_out, int out_size, void* d_ws, size_t ws_size,
                              hipStream_t stream) {
    const float* pos = (const float*)d_in[0];
    const float* neg = (const float*)d_in[1];
    const int* pos_classes = (const int*)d_in[2];
    const int* target_class = (const int*)d_in[3];
    const float* Wp1 = (const float*)d_in[4];
    const float* bp1 = (const float*)d_in[5];
    const float* Wp2 = (const float*)d_in[6];
    const float* bp2 = (const float*)d_in[7];
    const float* Wu1 = (const float*)d_in[8];
    const float* bu1 = (const float*)d_in[9];
    const float* Wu2 = (const float*)d_in[10];
    const float* bu2 = (const float*)d_in[11];

    float* ws = (float*)d_ws;
    float* HU0 = ws;                       // 64*128*128 = 1048576
    float* HP0 = HU0 + 1048576;            // 1048576
    float* HP1 = HP0 + 1048576;            // 1048576
    float* HU1n = HP1 + 1048576;           // 64*64*128 = 524288
    float* t0 = HU1n + 524288;             // 8192
    float* total = t0 + 8192;              // 32*16384 = 524288
    float* tA = total + 524288;            // 2048
    float* tB = tA + 2048;                 // 2048
    float* hp0g = tB + 2048;               // 16*64*128 = 131072
    float* hp1g = hp0g + 131072;           // 131072
    int* subA = (int*)(hp1g + 131072);     // 4096 ints
    int* subB = subA + 4096;               // 4096 ints
    int* inds = subB + 4096;               // 2048 ints

    // Stage 1: four GEMMs (linear projections; shared across all tree levels)
    gemm_rxd<<<128, 256, 0, stream>>>(pos, Wu1, HU0);                 // pos @ Wu1[:D]
    gemm_rxd<<<64, 256, 0, stream>>>(neg, Wu1 + D_ * H_, HU1n);       // neg @ Wu1[D:]
    gemm_rxd<<<128, 256, 0, stream>>>(pos, Wp1, HP0);                 // pos @ Wp1[:D]
    gemm_rxd<<<128, 256, 0, stream>>>(pos, Wp1 + D_ * H_, HP1);       // pos @ Wp1[D:]

    // Stage 2: unary energies (initial totals, since pe=0 and all scales=1)
    ue_kernel<<<dim3(BK_, N_ / 32), 256, 0, stream>>>(HU0, HU1n, bu1, Wu2, bu2, t0);

    // Level 0: Bn=32, M=128, S=1 (identity subs)
    score_kernel<<<dim3(32, 4, 2), 256, 0, stream>>>(
        HP0, 2 * N_ * H_, HP1 + N_ * H_, 2 * N_ * H_,
        t0, 2 * N_, t0 + N_, 2 * N_, bp1, Wp2, bp2, total, 128);
    topk_kernel<<<32, 256, 0, stream>>>(total, 128 * 128, 64, inds);
    select_kernel<<<32, 64, 0, stream>>>(total, 128, inds, 64, nullptr, 0, subA, tA);

    // Level 1: Bn=16, M=64, S=2
    gather_kernel<<<dim3(16, 64), 128, 0, stream>>>(HP0, subA, hp0g, 2, 0);
    gather_kernel<<<dim3(16, 64), 128, 0, stream>>>(HP1, subA, hp1g, 2, 1);
    score_kernel<<<dim3(16, 2, 1), 256, 0, stream>>>(
        hp0g, 64 * H_, hp1g, 64 * H_,
        tA, 128, tA + 64, 128, bp1, Wp2, bp2, total, 64);
    topk_kernel<<<16, 256, 0, stream>>>(total, 64 * 64, 64, inds);
    select_kernel<<<16, 64, 0, stream>>>(total, 64, inds, 64, subA, 2, subB, tB);

    // Level 2: Bn=8, M=64, S=4, topk=1
    gather_kernel<<<dim3(8, 64), 128, 0, stream>>>(HP0, subB, hp0g, 4, 0);
    gather_kernel<<<dim3(8, 64), 128, 0, stream>>>(HP1, subB, hp1g, 4, 1);
    score_kernel<<<dim3(8, 2, 1), 256, 0, stream>>>(
        hp0g, 64 * H_, hp1g, 64 * H_,
        tB, 128, tB + 64, 128, bp1, Wp2, bp2, total, 64);
    topk_kernel<<<8, 256, 0, stream>>>(total, 64 * 64, 1, inds);
    select_kernel<<<8, 64, 0, stream>>>(total, 64, inds, 1, subB, 4, subA, tA);

    // Output
    out_kernel<<<33, 256, 0, stream>>>(subA, pos_classes, target_class, (float*)d_out);
}

// Round 2
// 330.775 us; speedup vs baseline: 3.1380x; 3.1380x over previous
//
#include <hip/hip_runtime.h>
#include <stdint.h>

#define B_ 8
#define K_ 8
#define N_ 128
#define D_ 256
#define H_ 128
#define NNEG_ 64
#define NTOP_ 64
#define BK_ 64

// ---------------------------------------------------------------------------
// GEMM: OUT[r,h] = sum_d A[r*D+d] * W[d*H+h].  rows multiple of 64.
// Block: 256 threads (16x16), tile 64 rows x 128 cols, K-chunks of 16.
// ---------------------------------------------------------------------------
__global__ __launch_bounds__(256) void gemm_rxd(const float* __restrict__ A,
                                                const float* __restrict__ W,
                                                float* __restrict__ OUT) {
    __shared__ float As[64][17];
    __shared__ float Bs[16][128];
    int t = threadIdx.x;
    int tx = t & 15, ty = t >> 4;
    int rb = blockIdx.x * 64;
    float acc[4][8];
#pragma unroll
    for (int i = 0; i < 4; ++i)
#pragma unroll
        for (int j = 0; j < 8; ++j) acc[i][j] = 0.f;

    for (int k0 = 0; k0 < D_; k0 += 16) {
        {
            int row = t >> 2, kq = (t & 3) * 4;
            const float4 av = *(const float4*)&A[(size_t)(rb + row) * D_ + k0 + kq];
            As[row][kq + 0] = av.x; As[row][kq + 1] = av.y;
            As[row][kq + 2] = av.z; As[row][kq + 3] = av.w;
        }
        {
            int flat = t * 8;
            int kr = flat >> 7, hc = flat & 127;
            float4 b0 = *(const float4*)&W[(size_t)(k0 + kr) * H_ + hc];
            float4 b1 = *(const float4*)&W[(size_t)(k0 + kr) * H_ + hc + 4];
            *(float4*)&Bs[kr][hc] = b0;
            *(float4*)&Bs[kr][hc + 4] = b1;
        }
        __syncthreads();
#pragma unroll
        for (int kk = 0; kk < 16; ++kk) {
            float a0 = As[ty * 4 + 0][kk], a1 = As[ty * 4 + 1][kk];
            float a2 = As[ty * 4 + 2][kk], a3 = As[ty * 4 + 3][kk];
            float bv[8];
            *(float4*)&bv[0] = *(const float4*)&Bs[kk][tx * 8];
            *(float4*)&bv[4] = *(const float4*)&Bs[kk][tx * 8 + 4];
#pragma unroll
            for (int j = 0; j < 8; ++j) {
                acc[0][j] += a0 * bv[j];
                acc[1][j] += a1 * bv[j];
                acc[2][j] += a2 * bv[j];
                acc[3][j] += a3 * bv[j];
            }
        }
        __syncthreads();
    }
#pragma unroll
    for (int i = 0; i < 4; ++i) {
        float4 o0 = {acc[i][0], acc[i][1], acc[i][2], acc[i][3]};
        float4 o1 = {acc[i][4], acc[i][5], acc[i][6], acc[i][7]};
        *(float4*)&OUT[(size_t)(rb + ty * 4 + i) * H_ + tx * 8] = o0;
        *(float4*)&OUT[(size_t)(rb + ty * 4 + i) * H_ + tx * 8 + 4] = o1;
    }
}

// ---------------------------------------------------------------------------
// ue: t0[bk,m] = (1/64) * sum_n sum_h relu(HU0[bk,m,h]+HU1n[bk,n,h]+bu1[h])*wu2[h] + bu2
// grid (BK, N/32), block 256.  Each thread: 4 m's x 2 n's.
// ---------------------------------------------------------------------------
__global__ __launch_bounds__(256) void ue_kernel(const float* __restrict__ HU0,
                                                 const float* __restrict__ HU1n,
                                                 const float* __restrict__ bu1,
                                                 const float* __restrict__ Wu2,
                                                 const float* __restrict__ bu2v,
                                                 float* __restrict__ t0) {
    __shared__ float Ls[32][129];
    __shared__ float Rs[64][129];
    __shared__ float ws[128];
    __shared__ float red[32][33];
    int bk = blockIdx.x, mt = blockIdx.y;
    int t = threadIdx.x;
    for (int i = t; i < 64 * 128; i += 256) {
        int n = i >> 7, h = i & 127;
        Rs[n][h] = HU1n[(size_t)(bk * NNEG_ + n) * H_ + h];
    }
    for (int i = t; i < 32 * 128; i += 256) {
        int m = i >> 7, h = i & 127;
        Ls[m][h] = HU0[(size_t)(bk * N_ + mt * 32 + m) * H_ + h] + bu1[h];
    }
    if (t < 128) ws[t] = Wu2[t];
    __syncthreads();

    int tm = t & 7;    // m group (4 m's each)
    int tn = t >> 3;   // 0..31, 2 n's each
    const float* l0 = &Ls[tm * 4 + 0][0];
    const float* l1 = &Ls[tm * 4 + 1][0];
    const float* l2 = &Ls[tm * 4 + 2][0];
    const float* l3 = &Ls[tm * 4 + 3][0];
    const float* r0 = &Rs[tn * 2 + 0][0];
    const float* r1 = &Rs[tn * 2 + 1][0];
    float a00 = 0.f, a01 = 0.f, a10 = 0.f, a11 = 0.f;
    float a20 = 0.f, a21 = 0.f, a30 = 0.f, a31 = 0.f;
#pragma unroll 4
    for (int h = 0; h < 128; ++h) {
        float w = ws[h];
        float b0 = r0[h], b1 = r1[h];
        float a0 = l0[h], a1 = l1[h], a2 = l2[h], a3 = l3[h];
        float v;
        v = a0 + b0; v = v > 0.f ? v : 0.f; a00 += v * w;
        v = a0 + b1; v = v > 0.f ? v : 0.f; a01 += v * w;
        v = a1 + b0; v = v > 0.f ? v : 0.f; a10 += v * w;
        v = a1 + b1; v = v > 0.f ? v : 0.f; a11 += v * w;
        v = a2 + b0; v = v > 0.f ? v : 0.f; a20 += v * w;
        v = a2 + b1; v = v > 0.f ? v : 0.f; a21 += v * w;
        v = a3 + b0; v = v > 0.f ? v : 0.f; a30 += v * w;
        v = a3 + b1; v = v > 0.f ? v : 0.f; a31 += v * w;
    }
    red[tm * 4 + 0][tn] = a00 + a01;
    red[tm * 4 + 1][tn] = a10 + a11;
    red[tm * 4 + 2][tn] = a20 + a21;
    red[tm * 4 + 3][tn] = a30 + a31;
    __syncthreads();
    if (t < 32) {
        float s = 0.f;
        for (int q = 0; q < 32; ++q) s += red[t][q];
        t0[bk * N_ + mt * 32 + t] = s * (1.0f / NNEG_) + bu2v[0];
    }
}

// ---------------------------------------------------------------------------
// score+total: total[b, m0*M+m1] = tL[m0] + tR[m1] - (dot(relu(L+R+bp1),wp2)+bp2)
// grid (Bn, M/32, M/64), block 256.
// ---------------------------------------------------------------------------
__global__ __launch_bounds__(256) void score_kernel(
    const float* __restrict__ Lp, int Lbs,
    const float* __restrict__ Rp, int Rbs,
    const float* __restrict__ tLp, int tLbs,
    const float* __restrict__ tRp, int tRbs,
    const float* __restrict__ bp1, const float* __restrict__ Wp2,
    const float* __restrict__ bp2, float* __restrict__ total, int M) {
    int b = blockIdx.x, m0t = blockIdx.y, m1t = blockIdx.z;
    const float* L = Lp + (size_t)b * Lbs + m0t * 32 * H_;
    const float* R = Rp + (size_t)b * Rbs + m1t * 64 * H_;
    __shared__ float Ls[32][129];
    __shared__ float Rs[64][129];
    __shared__ float ws[128];
    int t = threadIdx.x;
    for (int i = t; i < 64 * 128; i += 256) {
        int n = i >> 7, h = i & 127;
        Rs[n][h] = R[(size_t)n * H_ + h];
    }
    for (int i = t; i < 32 * 128; i += 256) {
        int m = i >> 7, h = i & 127;
        Ls[m][h] = L[(size_t)m * H_ + h] + bp1[h];
    }
    if (t < 128) ws[t] = Wp2[t];
    __syncthreads();

    int tm = t & 7, tn = t >> 3;
    const float* l0 = &Ls[tm * 4 + 0][0];
    const float* l1 = &Ls[tm * 4 + 1][0];
    const float* l2 = &Ls[tm * 4 + 2][0];
    const float* l3 = &Ls[tm * 4 + 3][0];
    const float* r0 = &Rs[tn * 2 + 0][0];
    const float* r1 = &Rs[tn * 2 + 1][0];
    float a00 = 0.f, a01 = 0.f, a10 = 0.f, a11 = 0.f;
    float a20 = 0.f, a21 = 0.f, a30 = 0.f, a31 = 0.f;
#pragma unroll 4
    for (int h = 0; h < 128; ++h) {
        float w = ws[h];
        float b0 = r0[h], b1 = r1[h];
        float a0 = l0[h], a1 = l1[h], a2 = l2[h], a3 = l3[h];
        float v;
        v = a0 + b0; v = v > 0.f ? v : 0.f; a00 += v * w;
        v = a0 + b1; v = v > 0.f ? v : 0.f; a01 += v * w;
        v = a1 + b0; v = v > 0.f ? v : 0.f; a10 += v * w;
        v = a1 + b1; v = v > 0.f ? v : 0.f; a11 += v * w;
        v = a2 + b0; v = v > 0.f ? v : 0.f; a20 += v * w;
        v = a2 + b1; v = v > 0.f ? v : 0.f; a21 += v * w;
        v = a3 + b0; v = v > 0.f ? v : 0.f; a30 += v * w;
        v = a3 + b1; v = v > 0.f ? v : 0.f; a31 += v * w;
    }
    float bp2v = bp2[0];
    const float* tL = tLp + (size_t)b * tLbs;
    const float* tR = tRp + (size_t)b * tRbs;
    float* orow = total + (size_t)b * M * M;
    float accs[4][2] = {{a00, a01}, {a10, a11}, {a20, a21}, {a30, a31}};
#pragma unroll
    for (int i = 0; i < 4; ++i) {
        int m0 = m0t * 32 + tm * 4 + i;
        float tl = tL[m0];
#pragma unroll
        for (int j = 0; j < 2; ++j) {
            int m1 = m1t * 64 + tn * 2 + j;
            orow[(size_t)m0 * M + m1] = tl + tR[m1] - (accs[i][j] + bp2v);
        }
    }
}

// ---------------------------------------------------------------------------
// gather: outg[b,m,h] = (1/S) sum_s SRC[(b*2S + c*S + s)*N*H + sub_prev[(2b+c)*64*S + m*S + s]*H + h]
// grid (Bn, 64), block 128.
// ---------------------------------------------------------------------------
__global__ void gather_kernel(const float* __restrict__ SRC,
                              const int* __restrict__ sub_prev,
                              float* __restrict__ outg, int S, int c) {
    int b = blockIdx.x, m = blockIdx.y, h = threadIdx.x;
    const int* srow = sub_prev + (size_t)((2 * b + c) * 64 + m) * S;
    int base_bk = b * 2 * S + c * S;
    float s = 0.f;
    for (int i = 0; i < S; ++i) {
        int leaf = srow[i];
        s += SRC[(size_t)(base_bk + i) * N_ * H_ + (size_t)leaf * H_ + h];
    }
    outg[(size_t)(b * 64 + m) * H_ + h] = s / (float)S;
}

// ---------------------------------------------------------------------------
// top-k via radix select (exact jax.lax.top_k semantics: ascending total,
// ties -> lower index).  key = (sortable_f32 << 32) | idx.
// 4x 8-bit radix levels find exact threshold value T of the k-th smallest;
// collect all keys with value <= T (>= k of them, ~k in practice); bitonic
// sort 256 candidates in LDS; first k are the answer in exact order.
// grid (Bn), block 256.
// ---------------------------------------------------------------------------
__global__ __launch_bounds__(256) void topk_kernel(const float* __restrict__ total,
                                                   int L, int topk,
                                                   int* __restrict__ inds) {
    int b = blockIdx.x;
    const float* row = total + (size_t)b * L;
    int t = threadIdx.x;

    if (topk == 1) {
        __shared__ unsigned long long red[256];
        unsigned long long lm = ~0ull;
        for (int i = t; i < L; i += 256) {
            unsigned u = __float_as_uint(row[i]);
            u = (u & 0x80000000u) ? ~u : (u | 0x80000000u);
            unsigned long long k = ((unsigned long long)u << 32) | (unsigned)i;
            lm = k < lm ? k : lm;
        }
        red[t] = lm;
        __syncthreads();
        for (int s = 128; s > 0; s >>= 1) {
            if (t < s && red[t + s] < red[t]) red[t] = red[t + s];
            __syncthreads();
        }
        if (t == 0) inds[b * 64] = (int)(red[0] & 0xFFFFFFFFu);
        return;
    }

    __shared__ unsigned int hist[256];
    __shared__ unsigned int pscan[256];
    __shared__ unsigned int s_prefix, s_kneed, s_count;
    __shared__ unsigned long long cand[256];

    if (t == 0) { s_prefix = 0u; s_kneed = (unsigned)topk; }
    __syncthreads();

    for (int shift = 24; shift >= 0; shift -= 8) {
        hist[t] = 0u;
        __syncthreads();
        unsigned prefix = s_prefix;
        for (int i = t; i < L; i += 256) {
            unsigned u = __float_as_uint(row[i]);
            u = (u & 0x80000000u) ? ~u : (u | 0x80000000u);
            bool ok = (shift == 24) ? true : ((u >> (shift + 8)) == prefix);
            if (ok) atomicAdd(&hist[(u >> shift) & 255], 1u);
        }
        __syncthreads();
        // inclusive Hillis-Steele scan of hist -> pscan
        unsigned v = hist[t];
        pscan[t] = v;
        __syncthreads();
        for (int off = 1; off < 256; off <<= 1) {
            unsigned add = (t >= off) ? pscan[t - off] : 0u;
            __syncthreads();
            pscan[t] += add;
            __syncthreads();
        }
        unsigned kneed = s_kneed;
        unsigned below = (t == 0) ? 0u : pscan[t - 1];
        if (pscan[t] >= kneed && below < kneed) {
            s_prefix = (prefix << 8) | (unsigned)t;
            s_kneed = kneed - below;
        }
        __syncthreads();
    }

    unsigned T = s_prefix;  // exact sortable value of the k-th smallest
    if (t == 0) s_count = 0u;
    __syncthreads();
    for (int i = t; i < L; i += 256) {
        unsigned u = __float_as_uint(row[i]);
        u = (u & 0x80000000u) ? ~u : (u | 0x80000000u);
        if (u <= T) {
            unsigned p = atomicAdd(&s_count, 1u);
            if (p < 256u) cand[p] = ((unsigned long long)u << 32) | (unsigned)i;
        }
    }
    __syncthreads();
    unsigned cnt = s_count < 256u ? s_count : 256u;
    if ((unsigned)t >= cnt) cand[t] = ~0ull;
    __syncthreads();
    // bitonic sort 256 u64 ascending, one element per thread
    for (int ksz = 2; ksz <= 256; ksz <<= 1) {
        for (int j = ksz >> 1; j > 0; j >>= 1) {
            int ixj = t ^ j;
            if (ixj > t) {
                unsigned long long a = cand[t], c = cand[ixj];
                bool up = ((t & ksz) == 0);
                if ((a > c) == up) { cand[t] = c; cand[ixj] = a; }
            }
            __syncthreads();
        }
    }
    if (t < topk) inds[b * 64 + t] = (int)(cand[t] & 0xFFFFFFFFu);
}

// ---------------------------------------------------------------------------
// select: propagate totals and subtree leaf lists for the selected candidates.
// S==0 means level 0 (identity sub).  grid (Bn), block 64.
// ---------------------------------------------------------------------------
__global__ void select_kernel(const float* __restrict__ total, int M,
                              const int* __restrict__ inds, int topk,
                              const int* __restrict__ sub_prev, int S,
                              int* __restrict__ sub_new,
                              float* __restrict__ t_new) {
    int b = blockIdx.x;
    int e = threadIdx.x;
    if (e >= topk) return;
    int j = inds[b * 64 + e];
    int p0 = j / M, p1 = j % M;
    t_new[b * 64 + e] = total[(size_t)b * M * M + j];
    int Sp = (S == 0) ? 1 : S;
    int* orow = sub_new + (size_t)(b * topk + e) * 2 * Sp;
    if (S == 0) {
        orow[0] = p0;
        orow[1] = p1;
    } else {
        const int* s0 = sub_prev + (size_t)((2 * b) * 64 + p0) * S;
        const int* s1 = sub_prev + (size_t)((2 * b + 1) * 64 + p1) * S;
        for (int s = 0; s < S; ++s) { orow[s] = s0[s]; orow[S + s] = s1[s]; }
    }
}

// ---------------------------------------------------------------------------
// output: out[0:64] = final leaf indices (as float), out[64:8256] = is_target.
// ---------------------------------------------------------------------------
__global__ void out_kernel(const int* __restrict__ sub_final,
                           const int* __restrict__ pos_classes,
                           const int* __restrict__ target_class,
                           float* __restrict__ out) {
    int t = blockIdx.x * 256 + threadIdx.x;
    if (t < 64) {
        out[t] = (float)sub_final[t];
    } else if (t < 64 + B_ * K_ * N_) {
        int idx = t - 64;
        int bq = idx >> 10;  // / (K_*N_)
        out[t] = (pos_classes[idx] == target_class[bq]) ? 1.0f : 0.0f;
    }
}

extern "C" void kernel_launch(void* const* d_in, const int* in_sizes, int n_in,
                              void* d_out, int out_size, void* d_ws, size_t ws_size,
                              hipStream_t stream) {
    const float* pos = (const float*)d_in[0];
    const float* neg = (const float*)d_in[1];
    const int* pos_classes = (const int*)d_in[2];
    const int* target_class = (const int*)d_in[3];
    const float* Wp1 = (const float*)d_in[4];
    const float* bp1 = (const float*)d_in[5];
    const float* Wp2 = (const float*)d_in[6];
    const float* bp2 = (const float*)d_in[7];
    const float* Wu1 = (const float*)d_in[8];
    const float* bu1 = (const float*)d_in[9];
    const float* Wu2 = (const float*)d_in[10];
    const float* bu2 = (const float*)d_in[11];

    float* ws = (float*)d_ws;
    float* HU0 = ws;                       // 64*128*128 = 1048576
    float* HP0 = HU0 + 1048576;            // 1048576
    float* HP1 = HP0 + 1048576;            // 1048576
    float* HU1n = HP1 + 1048576;           // 64*64*128 = 524288
    float* t0 = HU1n + 524288;             // 8192
    float* total = t0 + 8192;              // 32*16384 = 524288
    float* tA = total + 524288;            // 2048
    float* tB = tA + 2048;                 // 2048
    float* hp0g = tB + 2048;               // 16*64*128 = 131072
    float* hp1g = hp0g + 131072;           // 131072
    int* subA = (int*)(hp1g + 131072);     // 4096 ints
    int* subB = subA + 4096;               // 4096 ints
    int* inds = subB + 4096;               // 2048 ints

    // Stage 1: four GEMMs (linear projections; shared across all tree levels)
    gemm_rxd<<<128, 256, 0, stream>>>(pos, Wu1, HU0);                 // pos @ Wu1[:D]
    gemm_rxd<<<64, 256, 0, stream>>>(neg, Wu1 + D_ * H_, HU1n);       // neg @ Wu1[D:]
    gemm_rxd<<<128, 256, 0, stream>>>(pos, Wp1, HP0);                 // pos @ Wp1[:D]
    gemm_rxd<<<128, 256, 0, stream>>>(pos, Wp1 + D_ * H_, HP1);       // pos @ Wp1[D:]

    // Stage 2: unary energies (initial totals, since pe=0 and all scales=1)
    ue_kernel<<<dim3(BK_, N_ / 32), 256, 0, stream>>>(HU0, HU1n, bu1, Wu2, bu2, t0);

    // Level 0: Bn=32, M=128, S=1 (identity subs)
    score_kernel<<<dim3(32, 4, 2), 256, 0, stream>>>(
        HP0, 2 * N_ * H_, HP1 + N_ * H_, 2 * N_ * H_,
        t0, 2 * N_, t0 + N_, 2 * N_, bp1, Wp2, bp2, total, 128);
    topk_kernel<<<32, 256, 0, stream>>>(total, 128 * 128, 64, inds);
    select_kernel<<<32, 64, 0, stream>>>(total, 128, inds, 64, nullptr, 0, subA, tA);

    // Level 1: Bn=16, M=64, S=2
    gather_kernel<<<dim3(16, 64), 128, 0, stream>>>(HP0, subA, hp0g, 2, 0);
    gather_kernel<<<dim3(16, 64), 128, 0, stream>>>(HP1, subA, hp1g, 2, 1);
    score_kernel<<<dim3(16, 2, 1), 256, 0, stream>>>(
        hp0g, 64 * H_, hp1g, 64 * H_,
        tA, 128, tA + 64, 128, bp1, Wp2, bp2, total, 64);
    topk_kernel<<<16, 256, 0, stream>>>(total, 64 * 64, 64, inds);
    select_kernel<<<16, 64, 0, stream>>>(total, 64, inds, 64, subA, 2, subB, tB);

    // Level 2: Bn=8, M=64, S=4, topk=1
    gather_kernel<<<dim3(8, 64), 128, 0, stream>>>(HP0, subB, hp0g, 4, 0);
    gather_kernel<<<dim3(8, 64), 128, 0, stream>>>(HP1, subB, hp1g, 4, 1);
    score_kernel<<<dim3(8, 2, 1), 256, 0, stream>>>(
        hp0g, 64 * H_, hp1g, 64 * H_,
        tB, 128, tB + 64, 128, bp1, Wp2, bp2, total, 64);
    topk_kernel<<<8, 256, 0, stream>>>(total, 64 * 64, 1, inds);
    select_kernel<<<8, 64, 0, stream>>>(total, 64, inds, 1, subB, 4, subA, tA);

    // Output
    out_kernel<<<33, 256, 0, stream>>>(subA, pos_classes, target_class, (float*)d_out);
}